// Round 3
// baseline (2707.528 us; speedup 1.0000x reference)
//
#include <hip/hip_runtime.h>
#include <math.h>

// Problem constants
constexpr int BB = 2, TT = 2048, CC = 1024, HH = 16, HD = 64, EE = 8, FF = 4096;
constexpr int BT = BB * TT;     // 4096 tokens
constexpr int FFC = 2048;       // FF chunk size (2 chunks), hbuf held in bf16

// Workspace layout (units of 4 bytes). Peak ~= 50.5 MB (same as prior rounds).
constexpr size_t W = (size_t)BT * CC;              // 4,194,304 words
constexpr size_t OFF_Q    = 0;
constexpr size_t OFF_K    = W;
constexpr size_t OFF_V    = 2 * W;
constexpr size_t SM_BASE  = 3 * W;
constexpr size_t SM_GATES = SM_BASE;               // float[8192]
constexpr size_t SM_EIDS  = SM_BASE + 8192;        // int[8192]
constexpr size_t SM_STOK  = SM_BASE + 16384;       // int[8192]
constexpr size_t SM_SGATE = SM_BASE + 24576;       // float[8192]
constexpr size_t SM_CNT   = SM_BASE + 32768;       // int[8]
constexpr size_t SM_OFFS  = SM_BASE + 32776;       // int[8]
constexpr size_t SM_CUR   = SM_BASE + 32784;       // int[8]

typedef short bf16x8 __attribute__((ext_vector_type(8)));
typedef float f32x4  __attribute__((ext_vector_type(4)));

__device__ __forceinline__ float gelu_exact(float v) {
    return 0.5f * v * (1.0f + erff(v * 0.70710678118654752440f));
}

__device__ __forceinline__ short f2bf(float f) {   // RNE fp32->bf16
    unsigned u = __float_as_uint(f);
    unsigned r = 0x7fffu + ((u >> 16) & 1u);
    return (short)((u + r) >> 16);
}

__device__ __forceinline__ bf16x8 pack8(float4 a, float4 b) {
    bf16x8 o;
    o[0] = f2bf(a.x); o[1] = f2bf(a.y); o[2] = f2bf(a.z); o[3] = f2bf(a.w);
    o[4] = f2bf(b.x); o[5] = f2bf(b.y); o[6] = f2bf(b.z); o[7] = f2bf(b.w);
    return o;
}

__device__ __forceinline__ void f4a(float4 v, float* a) {
    a[0] = v.x; a[1] = v.y; a[2] = v.z; a[3] = v.w;
}

// XOR swizzle for [64][64] fp32 LDS tiles: float4-slot ^ (row>>2).
// Spreads stride-256B row-major column reads across all 8 bank-groups.
__device__ __forceinline__ int SW(int r, int c4) {
    return (((c4 >> 2) ^ ((r >> 2) & 15)) << 2);
}

// =================== fp32 SGEMM core, 128x128 tile, 8x8 acc ===================
// 256 threads. Thread owns rows {tr4..tr4+3, +64}, cols {tc4..tc4+3, +64}.
// Register-prefetched staging (issue-early / write-late): global loads for
// K-step k0+16 are issued right after the staging barrier of k0 and ride under
// the 16x64-FMA compute phase. Same ascending-k fmaf chain per output element
// -> bitwise-identical results (routing path preserved).
__device__ __forceinline__ void sgemm128_core(const float* __restrict__ ap,
                                              const float* __restrict__ bp0,
                                              const float* __restrict__ bp1,
                                              long bks, int Kd, float acc[8][8],
                                              float (*As)[128], float (*Bs)[128]) {
    const int t    = threadIdx.x;
    const int kb   = (t & 1) << 3;       // A: k sub-block 0 or 8
    const int mrow = t >> 1;             // A: tile row 0..127
    const int kq   = t >> 4;             // B: k row 0..15
    const int c16  = (t & 15) << 2;      // B: f4 col within 64
    const int tr4  = (t >> 4) << 2, tc4 = (t & 15) << 2;
    // preload k0 = 0
    float4 a0 = *(const float4*)(ap + kb);
    float4 a1 = *(const float4*)(ap + kb + 4);
    float4 b0 = *(const float4*)(bp0);
    float4 b1 = *(const float4*)(bp1);
    for (int k0 = 0; k0 < Kd; k0 += 16) {
        __syncthreads();
        As[kb + 0][mrow] = a0.x; As[kb + 1][mrow] = a0.y;
        As[kb + 2][mrow] = a0.z; As[kb + 3][mrow] = a0.w;
        As[kb + 4][mrow] = a1.x; As[kb + 5][mrow] = a1.y;
        As[kb + 6][mrow] = a1.z; As[kb + 7][mrow] = a1.w;
        *(float4*)&Bs[kq][c16]      = b0;
        *(float4*)&Bs[kq][c16 + 64] = b1;
        __syncthreads();
        if (k0 + 16 < Kd) {   // issue next-step loads; they complete under compute
            a0 = *(const float4*)(ap + k0 + 16 + kb);
            a1 = *(const float4*)(ap + k0 + 16 + kb + 4);
            b0 = *(const float4*)(bp0 + (size_t)(k0 + 16) * bks);
            b1 = *(const float4*)(bp1 + (size_t)(k0 + 16) * bks);
        }
#pragma unroll
        for (int kk = 0; kk < 16; ++kk) {
            float av[8], bv[8];
            f4a(*(const float4*)&As[kk][tr4],      av);
            f4a(*(const float4*)&As[kk][tr4 + 64], av + 4);
            f4a(*(const float4*)&Bs[kk][tc4],      bv);
            f4a(*(const float4*)&Bs[kk][tc4 + 64], bv + 4);
#pragma unroll
            for (int i = 0; i < 8; ++i)
#pragma unroll
                for (int j = 0; j < 8; ++j)
                    acc[i][j] = fmaf(av[i], bv[j], acc[i][j]);
        }
    }
}

// ---------------- QKV projection (fp32, 128x128 tiles) ------------------------
__global__ __launch_bounds__(256) void qkv_kernel(const float* __restrict__ x,
                                                  const float* __restrict__ Wq,
                                                  const float* __restrict__ Wk,
                                                  const float* __restrict__ Wv,
                                                  float* __restrict__ q,
                                                  float* __restrict__ k,
                                                  float* __restrict__ v) {
    __shared__ float As[16][128], Bs[16][128];
    const int mt = blockIdx.x, nt = blockIdx.y, wz = blockIdx.z;
    const float* Wm = (wz == 0) ? Wq : ((wz == 1) ? Wk : Wv);
    float* out = (wz == 0) ? q : ((wz == 1) ? k : v);
    const int t = threadIdx.x;
    const int kq = t >> 4, c16 = (t & 15) << 2;
    const float* ap  = x + (size_t)(mt * 128 + (t >> 1)) * CC;
    // columns nt*128 + [0,64) -> head 2nt; + [64,128) -> head 2nt+1
    const float* bp0 = Wm + ((size_t)(2 * nt)     * CC + kq) * HD + c16;
    const float* bp1 = Wm + ((size_t)(2 * nt + 1) * CC + kq) * HD + c16;
    float acc[8][8] = {};
    sgemm128_core(ap, bp0, bp1, HD, CC, acc, As, Bs);
    const int tr4 = (t >> 4) << 2, tc4 = (t & 15) << 2;
#pragma unroll
    for (int i = 0; i < 8; ++i) {
        const int row = mt * 128 + (i >> 2) * 64 + tr4 + (i & 3);
        float4 o0, o1;
        o0.x = acc[i][0]; o0.y = acc[i][1]; o0.z = acc[i][2]; o0.w = acc[i][3];
        o1.x = acc[i][4]; o1.y = acc[i][5]; o1.z = acc[i][6]; o1.w = acc[i][7];
        *(float4*)&out[(size_t)row * CC + nt * 128 + tc4]      = o0;
        *(float4*)&out[(size_t)row * CC + nt * 128 + 64 + tc4] = o1;
    }
}

// ---------------- plain GEMM + bias (fp32 out-projection) ---------------------
__global__ __launch_bounds__(256) void gemm_bias_kernel(const float* __restrict__ A,
                                                        const float* __restrict__ Bm,
                                                        const float* __restrict__ bias,
                                                        float* __restrict__ out,
                                                        int N, int Kd) {
    __shared__ float As[16][128], Bs[16][128];
    const int mt = blockIdx.x, nt = blockIdx.y;
    const int t = threadIdx.x;
    const int kq = t >> 4, c16 = (t & 15) << 2;
    const float* ap  = A + (size_t)(mt * 128 + (t >> 1)) * Kd;
    const float* bp0 = Bm + (size_t)kq * N + nt * 128 + c16;
    const float* bp1 = bp0 + 64;
    float acc[8][8] = {};
    sgemm128_core(ap, bp0, bp1, N, Kd, acc, As, Bs);
    const int tr4 = (t >> 4) << 2, tc4 = (t & 15) << 2;
    const float4 ba = *(const float4*)&bias[nt * 128 + tc4];
    const float4 bb = *(const float4*)&bias[nt * 128 + 64 + tc4];
#pragma unroll
    for (int i = 0; i < 8; ++i) {
        const int row = mt * 128 + (i >> 2) * 64 + tr4 + (i & 3);
        float4 o0, o1;
        o0.x = acc[i][0] + ba.x; o0.y = acc[i][1] + ba.y;
        o0.z = acc[i][2] + ba.z; o0.w = acc[i][3] + ba.w;
        o1.x = acc[i][4] + bb.x; o1.y = acc[i][5] + bb.y;
        o1.z = acc[i][6] + bb.z; o1.w = acc[i][7] + bb.w;
        *(float4*)&out[(size_t)row * N + nt * 128 + tc4]      = o0;
        *(float4*)&out[(size_t)row * N + nt * 128 + 64 + tc4] = o1;
    }
}

// ---------------- flash-style causal attention, single q-tile per block -------
// Same per-tile math / FMA order as the passing round (bitwise-identical
// routing path). Change vs r2: UNPAIRED q-tiles -> grid.x = 32 -> 1024 blocks
// -> 3 blocks/CU (LDS-limited) instead of 2 (grid-limited). Heavy tiles
// (qt large) dispatch first via qt = 31 - blockIdx.x for load balance.
__global__ __launch_bounds__(256) void attn_kernel(float* __restrict__ q,
                                                   const float* __restrict__ kbuf,
                                                   const float* __restrict__ vbuf) {
    __shared__ float Qs[64][64];
    __shared__ float Ks[64][64];
    __shared__ float Vs[64][64];
    float (*Ps)[64] = Ks;   // P overwrites K after QK^T consumed it
    const int h = blockIdx.y, b = blockIdx.z;
    const int t = threadIdx.x;
    const int tc4 = (t & 15) << 2, tr4 = (t >> 4) << 2;
    const size_t base = ((size_t)b * TT) * CC + h * HD;
    const int qt = (TT / 64 - 1) - blockIdx.x;   // heavy blocks dispatch first
#pragma unroll
    for (int it = 0; it < 4; ++it) {
        int fi = t + it * 256;
        int r = fi >> 4, c4 = (fi & 15) << 2;
        *(float4*)&Qs[r][SW(r, c4)] =
            *(const float4*)&q[base + (size_t)(qt * 64 + r) * CC + c4];
    }
    // preload K/V tile 0 into registers
    float4 kr[4], vr[4];
#pragma unroll
    for (int it = 0; it < 4; ++it) {
        int fi = t + it * 256;
        int s = fi >> 4, c4 = (fi & 15) << 2;
        kr[it] = *(const float4*)&kbuf[base + (size_t)s * CC + c4];
        vr[it] = *(const float4*)&vbuf[base + (size_t)s * CC + c4];
    }
    float o[4][4] = {};
    float m_r[4], l_r[4];
#pragma unroll
    for (int i = 0; i < 4; ++i) { m_r[i] = -INFINITY; l_r[i] = 0.0f; }

    for (int kt = 0; kt <= qt; ++kt) {
        __syncthreads();
#pragma unroll
        for (int it = 0; it < 4; ++it) {
            int fi = t + it * 256;
            int s = fi >> 4, c4 = (fi & 15) << 2;
            *(float4*)&Ks[s][SW(s, c4)] = kr[it];
            *(float4*)&Vs[s][SW(s, c4)] = vr[it];
        }
        __syncthreads();
        if (kt < qt) {   // prefetch next K/V tile; completes under compute
#pragma unroll
            for (int it = 0; it < 4; ++it) {
                int fi = t + it * 256;
                int s = fi >> 4, c4 = (fi & 15) << 2;
                kr[it] = *(const float4*)&kbuf[base + (size_t)((kt + 1) * 64 + s) * CC + c4];
                vr[it] = *(const float4*)&vbuf[base + (size_t)((kt + 1) * 64 + s) * CC + c4];
            }
        }
        float s4[4][4] = {};
        for (int d4 = 0; d4 < 64; d4 += 4) {
            float qa[4][4], ka[4][4];
#pragma unroll
            for (int i = 0; i < 4; ++i)
                f4a(*(const float4*)&Qs[tr4 + i][SW(tr4 + i, d4)], qa[i]);
#pragma unroll
            for (int j = 0; j < 4; ++j)
                f4a(*(const float4*)&Ks[tc4 + j][SW(tc4 + j, d4)], ka[j]);
#pragma unroll
            for (int i = 0; i < 4; ++i)
#pragma unroll
                for (int j = 0; j < 4; ++j) {
                    float a = s4[i][j];
                    a = fmaf(qa[i][0], ka[j][0], a);
                    a = fmaf(qa[i][1], ka[j][1], a);
                    a = fmaf(qa[i][2], ka[j][2], a);
                    a = fmaf(qa[i][3], ka[j][3], a);
                    s4[i][j] = a;
                }
        }
        const float scale = 0.03125f;  // C^-0.5 (faithful: full C)
#pragma unroll
        for (int i = 0; i < 4; ++i)
#pragma unroll
            for (int j = 0; j < 4; ++j) {
                float sv = s4[i][j] * scale;
                if (kt == qt && (tc4 + j) > (tr4 + i)) sv = -INFINITY;
                s4[i][j] = sv;
            }
        float p4[4][4];
#pragma unroll
        for (int i = 0; i < 4; ++i) {
            float mt_i = fmaxf(fmaxf(s4[i][0], s4[i][1]), fmaxf(s4[i][2], s4[i][3]));
#pragma unroll
            for (int msk = 1; msk <= 8; msk <<= 1) mt_i = fmaxf(mt_i, __shfl_xor(mt_i, msk, 64));
            float m_new = fmaxf(m_r[i], mt_i);
            float alpha = expf(m_r[i] - m_new);
            float ls = 0.0f;
#pragma unroll
            for (int j = 0; j < 4; ++j) {
                float p = expf(s4[i][j] - m_new);
                p4[i][j] = p;
                ls += p;
            }
#pragma unroll
            for (int msk = 1; msk <= 8; msk <<= 1) ls += __shfl_xor(ls, msk, 64);
            l_r[i] = l_r[i] * alpha + ls;
            m_r[i] = m_new;
#pragma unroll
            for (int j = 0; j < 4; ++j) o[i][j] *= alpha;
        }
        __syncthreads();
#pragma unroll
        for (int i = 0; i < 4; ++i) {
            float4 pv;
            pv.x = p4[i][0]; pv.y = p4[i][1]; pv.z = p4[i][2]; pv.w = p4[i][3];
            *(float4*)&Ps[tr4 + i][SW(tr4 + i, tc4)] = pv;
        }
        __syncthreads();
        for (int s0 = 0; s0 < 64; s0 += 4) {
            float pa[4][4], va[4][4];
#pragma unroll
            for (int i = 0; i < 4; ++i)
                f4a(*(const float4*)&Ps[tr4 + i][SW(tr4 + i, s0)], pa[i]);
#pragma unroll
            for (int qq = 0; qq < 4; ++qq)
                f4a(*(const float4*)&Vs[s0 + qq][SW(s0 + qq, tc4)], va[qq]);
#pragma unroll
            for (int i = 0; i < 4; ++i)
#pragma unroll
                for (int j = 0; j < 4; ++j) {
                    float a = o[i][j];
                    a = fmaf(pa[i][0], va[0][j], a);
                    a = fmaf(pa[i][1], va[1][j], a);
                    a = fmaf(pa[i][2], va[2][j], a);
                    a = fmaf(pa[i][3], va[3][j], a);
                    o[i][j] = a;
                }
        }
    }
#pragma unroll
    for (int i = 0; i < 4; ++i) {
        const float inv = 1.0f / l_r[i];
        float4 o4;
        o4.x = o[i][0] * inv; o4.y = o[i][1] * inv; o4.z = o[i][2] * inv; o4.w = o[i][3] * inv;
        *(float4*)&q[base + (size_t)(qt * 64 + tr4 + i) * CC + tc4] = o4;
    }
}

// ======================= bf16 MFMA blocks (FFN only) ==========================
// Tile 128x128, BK=32, 256 threads = 4 waves 2x2, wave does 4x4 of 16x16x32.
// Register-prefetched staging: raw fp32 for step k0+32 loaded during compute of
// k0; f2bf conversion happens at the LDS-write phase (same values as before).
__device__ __forceinline__ void compute_step(short (*As)[40], short (*Bs)[40],
                                             f32x4 acc[4][4], int wm, int wn,
                                             int l15, int q8) {
    bf16x8 a[4], b[4];
#pragma unroll
    for (int i = 0; i < 4; ++i) a[i] = *(bf16x8*)&As[wm + i * 16 + l15][q8];
#pragma unroll
    for (int j = 0; j < 4; ++j) b[j] = *(bf16x8*)&Bs[wn + j * 16 + l15][q8];
#pragma unroll
    for (int i = 0; i < 4; ++i)
#pragma unroll
        for (int j = 0; j < 4; ++j)
            acc[i][j] = __builtin_amdgcn_mfma_f32_16x16x32_bf16(a[i], b[j], acc[i][j], 0, 0, 0);
}

#define MM_PROLOG                                                    \
    const int t = threadIdx.x, lane = t & 63, wid = t >> 6;          \
    const int wm = (wid >> 1) * 64, wn = (wid & 1) * 64;             \
    const int l15 = lane & 15, q8 = (lane >> 4) * 8;                 \
    const int arow = t >> 1, akh = (t & 1) * 16;                     \
    const int bn = t & 127, bkh = (t >> 7) * 16;

// ---------------- MoE FFN layer 1: gathered rows, +b1, exact GELU -> bf16 hbuf
__global__ __launch_bounds__(256) void mm_ffn1(const float* __restrict__ x1,
                                               const float* __restrict__ W1,
                                               const float* __restrict__ b1,
                                               const int* __restrict__ stok,
                                               const int* __restrict__ offs,
                                               const int* __restrict__ cnt,
                                               short* __restrict__ hbuf, int fbase) {
    __shared__ short As[128][40], Bs[128][40];
    const int e = blockIdx.z, mt = blockIdx.x, nt = blockIdx.y;
    const int ne = cnt[e];
    if (mt * 128 >= ne) return;
    MM_PROLOG
    const int off_e = offs[e];
    int rl = mt * 128 + arow;
    if (rl >= ne) rl = ne - 1;
    const int token = stok[off_e + rl];
    const float* ap = x1 + (size_t)token * CC;
    const float* bp = W1 + (size_t)e * CC * FF + fbase + nt * 128 + bn;
    f32x4 acc[4][4] = {};
    // preload k0 = 0
    float4 apf[4];
    float bpf[16];
#pragma unroll
    for (int qd = 0; qd < 4; ++qd) apf[qd] = *(const float4*)(ap + akh + 4 * qd);
#pragma unroll
    for (int kk = 0; kk < 16; ++kk) bpf[kk] = bp[(size_t)(bkh + kk) * FF];
    for (int k0 = 0; k0 < CC; k0 += 32) {
        __syncthreads();
        *(bf16x8*)&As[arow][akh]     = pack8(apf[0], apf[1]);
        *(bf16x8*)&As[arow][akh + 8] = pack8(apf[2], apf[3]);
        {
            bf16x8 o0, o1;
#pragma unroll
            for (int kk = 0; kk < 8; ++kk) { o0[kk] = f2bf(bpf[kk]); o1[kk] = f2bf(bpf[kk + 8]); }
            *(bf16x8*)&Bs[bn][bkh]     = o0;
            *(bf16x8*)&Bs[bn][bkh + 8] = o1;
        }
        __syncthreads();
        if (k0 + 32 < CC) {
#pragma unroll
            for (int qd = 0; qd < 4; ++qd)
                apf[qd] = *(const float4*)(ap + k0 + 32 + akh + 4 * qd);
#pragma unroll
            for (int kk = 0; kk < 16; ++kk)
                bpf[kk] = bp[(size_t)(k0 + 32 + bkh + kk) * FF];
        }
        compute_step(As, Bs, acc, wm, wn, l15, q8);
    }
    float bj[4];
#pragma unroll
    for (int j = 0; j < 4; ++j)
        bj[j] = b1[(size_t)e * FF + fbase + nt * 128 + wn + j * 16 + l15];
    const int colb = nt * 128 + wn;   // chunk-local column
#pragma unroll
    for (int i = 0; i < 4; ++i) {
#pragma unroll
        for (int r = 0; r < 4; ++r) {
            const int row = mt * 128 + wm + i * 16 + (lane >> 4) * 4 + r;
            if (row < ne) {
                short* orow = hbuf + (size_t)(off_e + row) * FFC + colb;
#pragma unroll
                for (int j = 0; j < 4; ++j)
                    orow[j * 16 + l15] = f2bf(gelu_exact(acc[i][j][r] + bj[j]));
            }
        }
    }
}

// ---------------- MoE FFN layer 2: gate-weighted atomic accumulate -----------
__global__ __launch_bounds__(256) void mm_ffn2(const short* __restrict__ hbuf,
                                               const float* __restrict__ W2,
                                               const float* __restrict__ b2,
                                               const int* __restrict__ stok,
                                               const float* __restrict__ sgate,
                                               const int* __restrict__ offs,
                                               const int* __restrict__ cnt,
                                               float* __restrict__ moe,
                                               int fbase, int first) {
    __shared__ short As[128][40], Bs[128][40];
    const int e = blockIdx.z, mt = blockIdx.x, nt = blockIdx.y;
    const int ne = cnt[e];
    if (mt * 128 >= ne) return;
    MM_PROLOG
    const int off_e = offs[e];
    int rl = mt * 128 + arow;
    if (rl >= ne) rl = ne - 1;
    const short* ap = hbuf + (size_t)(off_e + rl) * FFC;
    const float* bp = W2 + (size_t)e * FF * CC + (size_t)fbase * CC + nt * 128 + bn;
    f32x4 acc[4][4] = {};
    // preload k0 = 0
    bf16x8 a0pf = *(const bf16x8*)(ap + akh);
    bf16x8 a1pf = *(const bf16x8*)(ap + akh + 8);
    float bpf[16];
#pragma unroll
    for (int kk = 0; kk < 16; ++kk) bpf[kk] = bp[(size_t)(bkh + kk) * CC];
    for (int k0 = 0; k0 < FFC; k0 += 32) {
        __syncthreads();
        *(bf16x8*)&As[arow][akh]     = a0pf;
        *(bf16x8*)&As[arow][akh + 8] = a1pf;
        {
            bf16x8 o0, o1;
#pragma unroll
            for (int kk = 0; kk < 8; ++kk) { o0[kk] = f2bf(bpf[kk]); o1[kk] = f2bf(bpf[kk + 8]); }
            *(bf16x8*)&Bs[bn][bkh]     = o0;
            *(bf16x8*)&Bs[bn][bkh + 8] = o1;
        }
        __syncthreads();
        if (k0 + 32 < FFC) {
            a0pf = *(const bf16x8*)(ap + k0 + 32 + akh);
            a1pf = *(const bf16x8*)(ap + k0 + 32 + akh + 8);
#pragma unroll
            for (int kk = 0; kk < 16; ++kk)
                bpf[kk] = bp[(size_t)(k0 + 32 + bkh + kk) * CC];
        }
        compute_step(As, Bs, acc, wm, wn, l15, q8);
    }
    float bj[4];
    int colj[4];
#pragma unroll
    for (int j = 0; j < 4; ++j) {
        colj[j] = nt * 128 + wn + j * 16 + l15;
        bj[j] = first ? b2[(size_t)e * CC + colj[j]] : 0.0f;
    }
#pragma unroll
    for (int i = 0; i < 4; ++i) {
#pragma unroll
        for (int r = 0; r < 4; ++r) {
            const int row = mt * 128 + wm + i * 16 + (lane >> 4) * 4 + r;
            if (row < ne) {
                const int slot = off_e + row;
                const int token = stok[slot];
                const float g = sgate[slot];
                float* dst = moe + (size_t)token * CC;
#pragma unroll
                for (int j = 0; j < 4; ++j)
                    atomicAdd(dst + colj[j], g * (acc[i][j][r] + bj[j]));
            }
        }
    }
}

// ---------------- LayerNorm + residual ----------------------------------------
__device__ __forceinline__ float block_sum(float v, float* red) {
#pragma unroll
    for (int m = 32; m >= 1; m >>= 1) v += __shfl_xor(v, m, 64);
    const int w = threadIdx.x >> 6;
    __syncthreads();
    if ((threadIdx.x & 63) == 0) red[w] = v;
    __syncthreads();
    return red[0] + red[1] + red[2] + red[3];
}

__global__ __launch_bounds__(256) void ln_res_kernel(const float* __restrict__ src,
                                                     const float* __restrict__ res,
                                                     const float* __restrict__ gam,
                                                     const float* __restrict__ bet,
                                                     float* __restrict__ out) {
    __shared__ float red[4];
    const int row = blockIdx.x, t = threadIdx.x;
    const float4 sv = *(const float4*)&src[(size_t)row * CC + t * 4];
    const float total = block_sum(sv.x + sv.y + sv.z + sv.w, red);
    const float mean = total * (1.0f / CC);
    const float d0 = sv.x - mean, d1 = sv.y - mean, d2 = sv.z - mean, d3 = sv.w - mean;
    const float var = block_sum(d0 * d0 + d1 * d1 + d2 * d2 + d3 * d3, red) * (1.0f / CC);
    const float rstd = rsqrtf(var + 1e-5f);
    const float4 rv = *(const float4*)&res[(size_t)row * CC + t * 4];
    const float4 g4 = *(const float4*)&gam[t * 4];
    const float4 b4 = *(const float4*)&bet[t * 4];
    float4 o4;
    o4.x = rv.x + d0 * rstd * g4.x + b4.x;
    o4.y = rv.y + d1 * rstd * g4.y + b4.y;
    o4.z = rv.z + d2 * rstd * g4.z + b4.z;
    o4.w = rv.w + d3 * rstd * g4.w + b4.w;
    *(float4*)&out[(size_t)row * CC + t * 4] = o4;
}

// ---------------- router: noisy top-2 gates + per-expert counts ---------------
__global__ __launch_bounds__(256) void router_kernel(const float* __restrict__ x1,
                                                     const float* __restrict__ Wr,
                                                     const float* __restrict__ br,
                                                     const float* __restrict__ Wn,
                                                     const float* __restrict__ bn,
                                                     const float* __restrict__ noise,
                                                     float* __restrict__ gates,
                                                     int* __restrict__ eids,
                                                     int* __restrict__ counts) {
    __shared__ float xs[CC];
    __shared__ float part[256];
    __shared__ float dots[16];
    const int tk = blockIdx.x, t = threadIdx.x;
    *(float4*)&xs[t * 4] = *(const float4*)&x1[(size_t)tk * CC + t * 4];
    __syncthreads();
    const int o = t & 15, cs = t >> 4;
    float acc = 0.0f;
    if (o < 8) {
        for (int c = cs; c < CC; c += 16) acc += xs[c] * Wr[c * EE + o];
    } else {
        const int e = o - 8;
        for (int c = cs; c < CC; c += 16) acc += xs[c] * Wn[c * EE + e];
    }
    part[t] = acc;
    __syncthreads();
    if (t < 16) {
        float s = 0.0f;
        for (int i = 0; i < 16; ++i) s += part[t + 16 * i];
        dots[t] = s;
    }
    __syncthreads();
    if (t == 0) {
        float noisy[EE];
        for (int e = 0; e < EE; ++e) {
            const float lg = dots[e] + br[e];
            const float nl = dots[8 + e] + bn[e];
            const float sp = fmaxf(nl, 0.0f) + log1pf(expf(-fabsf(nl)));
            noisy[e] = lg + noise[(size_t)tk * EE + e] * sp;
        }
        int e1 = 0; float v1 = noisy[0];
        for (int e = 1; e < EE; ++e) if (noisy[e] > v1) { v1 = noisy[e]; e1 = e; }
        int e2 = -1; float v2 = -INFINITY;
        for (int e = 0; e < EE; ++e) if (e != e1 && noisy[e] > v2) { v2 = noisy[e]; e2 = e; }
        const float ex = expf(v2 - v1);
        const float inv = 1.0f / (1.0f + ex);
        gates[2 * tk] = inv; gates[2 * tk + 1] = ex * inv;
        eids[2 * tk] = e1; eids[2 * tk + 1] = e2;
        atomicAdd(&counts[e1], 1);
        atomicAdd(&counts[e2], 1);
    }
}

__global__ void zero_counts_kernel(int* __restrict__ cnt) {
    if (threadIdx.x < EE) cnt[threadIdx.x] = 0;
}

__global__ void offsets_kernel(const int* __restrict__ cnt, int* __restrict__ offs,
                               int* __restrict__ cur) {
    const int t = threadIdx.x;
    if (t == 0) {
        int a = 0;
        for (int e = 0; e < EE; ++e) { offs[e] = a; a += cnt[e]; }
    }
    if (t < EE) cur[t] = 0;
}

__global__ __launch_bounds__(256) void scatter_kernel(const int* __restrict__ eids,
                                                      const float* __restrict__ gates,
                                                      int* __restrict__ cur,
                                                      const int* __restrict__ offs,
                                                      int* __restrict__ slot_token,
                                                      float* __restrict__ slot_gate) {
    const int tk = blockIdx.x * 256 + threadIdx.x;
    if (tk >= BT) return;
#pragma unroll
    for (int ki = 0; ki < 2; ++ki) {
        const int e = eids[2 * tk + ki];
        const int idx = atomicAdd(&cur[e], 1);
        const int slot = offs[e] + idx;
        slot_token[slot] = tk;
        slot_gate[slot] = gates[2 * tk + ki];
    }
}

__global__ __launch_bounds__(256) void zero_kernel(float* __restrict__ p, int n4) {
    const int i = blockIdx.x * 256 + threadIdx.x;
    if (i < n4) ((float4*)p)[i] = make_float4(0.f, 0.f, 0.f, 0.f);
}

// ---------------- launch ------------------------------------------------------
extern "C" void kernel_launch(void* const* d_in, const int* in_sizes, int n_in,
                              void* d_out, int out_size, void* d_ws, size_t ws_size,
                              hipStream_t stream) {
    (void)in_sizes; (void)n_in; (void)out_size; (void)ws_size;
    const float* x    = (const float*)d_in[0];
    const float* Wq   = (const float*)d_in[1];
    const float* Wk   = (const float*)d_in[2];
    const float* Wv   = (const float*)d_in[3];
    const float* Wo   = (const float*)d_in[4];
    const float* bo   = (const float*)d_in[5];
    const float* ln1g = (const float*)d_in[6];
    const float* ln1b = (const float*)d_in[7];
    const float* Wr   = (const float*)d_in[8];
    const float* br   = (const float*)d_in[9];
    const float* Wn   = (const float*)d_in[10];
    const float* bn   = (const float*)d_in[11];
    const float* W1   = (const float*)d_in[12];
    const float* b1   = (const float*)d_in[13];
    const float* W2   = (const float*)d_in[14];
    const float* b2   = (const float*)d_in[15];
    const float* ln2g = (const float*)d_in[16];
    const float* ln2b = (const float*)d_in[17];
    const float* noise= (const float*)d_in[18];
    float* out = (float*)d_out;
    float* ws  = (float*)d_ws;
    int*   iws = (int*)d_ws;

    float* qb    = ws + OFF_Q;     // Q, then attn output (in-place)
    float* kb    = ws + OFF_K;
    float* vb    = ws + OFF_V;
    float* proj  = ws + OFF_V;     // V dead after attention
    float* x1    = out;            // x1 lives in d_out
    short* hbuf  = (short*)(ws + OFF_Q);  // spans Q+K regions: 8192 x 2048 bf16
    float* moe   = ws + OFF_V;     // proj dead after ln1
    float* gates = ws + SM_GATES;
    float* sgate = ws + SM_SGATE;
    int* eids  = iws + SM_EIDS;
    int* stok  = iws + SM_STOK;
    int* cnt   = iws + SM_CNT;
    int* offs  = iws + SM_OFFS;
    int* cur   = iws + SM_CUR;

    zero_counts_kernel<<<1, 64, 0, stream>>>(cnt);
    qkv_kernel<<<dim3(BT / 128, CC / 128, 3), 256, 0, stream>>>(x, Wq, Wk, Wv, qb, kb, vb);
    attn_kernel<<<dim3(TT / 64, HH, BB), 256, 0, stream>>>(qb, kb, vb);
    gemm_bias_kernel<<<dim3(BT / 128, CC / 128), 256, 0, stream>>>(qb, Wo, bo, proj, CC, CC);
    ln_res_kernel<<<BT, 256, 0, stream>>>(proj, x, ln1g, ln1b, x1);
    router_kernel<<<BT, 256, 0, stream>>>(x1, Wr, br, Wn, bn, noise, gates, eids, cnt);
    offsets_kernel<<<1, 64, 0, stream>>>(cnt, offs, cur);
    scatter_kernel<<<BT / 256, 256, 0, stream>>>(eids, gates, cur, offs, stok, sgate);
    zero_kernel<<<(BT * CC / 4 + 255) / 256, 256, 0, stream>>>(moe, BT * CC / 4);
    for (int ccnk = 0; ccnk < FF / FFC; ++ccnk) {
        mm_ffn1<<<dim3(2 * BT / 128, FFC / 128, EE), 256, 0, stream>>>(
            x1, W1, b1, stok, offs, cnt, hbuf, ccnk * FFC);
        mm_ffn2<<<dim3(2 * BT / 128, CC / 128, EE), 256, 0, stream>>>(
            hbuf, W2, b2, stok, sgate, offs, cnt, moe, ccnk * FFC, ccnk == 0 ? 1 : 0);
    }
    ln_res_kernel<<<BT, 256, 0, stream>>>(moe, x1, ln2g, ln2b, out);
}

// Round 4
// 2499.444 us; speedup vs baseline: 1.0833x; 1.0833x over previous
//
#include <hip/hip_runtime.h>
#include <math.h>

// Problem constants
constexpr int BB = 2, TT = 2048, CC = 1024, HH = 16, HD = 64, EE = 8, FF = 4096;
constexpr int BT = BB * TT;     // 4096 tokens
constexpr int FFC = 2048;       // FF chunk size (2 chunks), hbuf held in bf16

// Workspace layout (units of 4 bytes). Peak ~= 50.5 MB (same as prior rounds).
constexpr size_t W = (size_t)BT * CC;              // 4,194,304 words
constexpr size_t OFF_Q    = 0;
constexpr size_t OFF_K    = W;
constexpr size_t OFF_V    = 2 * W;
constexpr size_t SM_BASE  = 3 * W;
constexpr size_t SM_GATES = SM_BASE;               // float[8192]
constexpr size_t SM_EIDS  = SM_BASE + 8192;        // int[8192]
constexpr size_t SM_STOK  = SM_BASE + 16384;       // int[8192]
constexpr size_t SM_SGATE = SM_BASE + 24576;       // float[8192]
constexpr size_t SM_CNT   = SM_BASE + 32768;       // int[8]
constexpr size_t SM_OFFS  = SM_BASE + 32776;       // int[8]
constexpr size_t SM_CUR   = SM_BASE + 32784;       // int[8]
constexpr size_t SM_ACNT  = SM_BASE + 32792;       // int[1]  attn job counter

typedef short bf16x8 __attribute__((ext_vector_type(8)));
typedef float f32x4  __attribute__((ext_vector_type(4)));

__device__ __forceinline__ float gelu_exact(float v) {
    return 0.5f * v * (1.0f + erff(v * 0.70710678118654752440f));
}

__device__ __forceinline__ short f2bf(float f) {   // RNE fp32->bf16
    unsigned u = __float_as_uint(f);
    unsigned r = 0x7fffu + ((u >> 16) & 1u);
    return (short)((u + r) >> 16);
}

__device__ __forceinline__ bf16x8 pack8(float4 a, float4 b) {
    bf16x8 o;
    o[0] = f2bf(a.x); o[1] = f2bf(a.y); o[2] = f2bf(a.z); o[3] = f2bf(a.w);
    o[4] = f2bf(b.x); o[5] = f2bf(b.y); o[6] = f2bf(b.z); o[7] = f2bf(b.w);
    return o;
}

__device__ __forceinline__ void f4a(float4 v, float* a) {
    a[0] = v.x; a[1] = v.y; a[2] = v.z; a[3] = v.w;
}

// XOR swizzle for [64][64] fp32 LDS tiles: float4-slot ^ (row>>2).
// Spreads stride-256B row-major column reads across all 8 bank-groups.
__device__ __forceinline__ int SW(int r, int c4) {
    return (((c4 >> 2) ^ ((r >> 2) & 15)) << 2);
}

// =================== fp32 SGEMM core, 128x128 tile, 8x8 acc ===================
// 256 threads. Thread owns rows {tr4..tr4+3, +64}, cols {tc4..tc4+3, +64}.
// Register-prefetched staging (issue-early / write-late): global loads for
// K-step k0+16 are issued right after the staging barrier of k0 and ride under
// the 16x64-FMA compute phase. Same ascending-k fmaf chain per output element
// -> bitwise-identical results (routing path preserved).
__device__ __forceinline__ void sgemm128_core(const float* __restrict__ ap,
                                              const float* __restrict__ bp0,
                                              const float* __restrict__ bp1,
                                              long bks, int Kd, float acc[8][8],
                                              float (*As)[128], float (*Bs)[128]) {
    const int t    = threadIdx.x;
    const int kb   = (t & 1) << 3;       // A: k sub-block 0 or 8
    const int mrow = t >> 1;             // A: tile row 0..127
    const int kq   = t >> 4;             // B: k row 0..15
    const int c16  = (t & 15) << 2;      // B: f4 col within 64
    const int tr4  = (t >> 4) << 2, tc4 = (t & 15) << 2;
    // preload k0 = 0
    float4 a0 = *(const float4*)(ap + kb);
    float4 a1 = *(const float4*)(ap + kb + 4);
    float4 b0 = *(const float4*)(bp0);
    float4 b1 = *(const float4*)(bp1);
    for (int k0 = 0; k0 < Kd; k0 += 16) {
        __syncthreads();
        As[kb + 0][mrow] = a0.x; As[kb + 1][mrow] = a0.y;
        As[kb + 2][mrow] = a0.z; As[kb + 3][mrow] = a0.w;
        As[kb + 4][mrow] = a1.x; As[kb + 5][mrow] = a1.y;
        As[kb + 6][mrow] = a1.z; As[kb + 7][mrow] = a1.w;
        *(float4*)&Bs[kq][c16]      = b0;
        *(float4*)&Bs[kq][c16 + 64] = b1;
        __syncthreads();
        if (k0 + 16 < Kd) {   // issue next-step loads; they complete under compute
            a0 = *(const float4*)(ap + k0 + 16 + kb);
            a1 = *(const float4*)(ap + k0 + 16 + kb + 4);
            b0 = *(const float4*)(bp0 + (size_t)(k0 + 16) * bks);
            b1 = *(const float4*)(bp1 + (size_t)(k0 + 16) * bks);
        }
#pragma unroll
        for (int kk = 0; kk < 16; ++kk) {
            float av[8], bv[8];
            f4a(*(const float4*)&As[kk][tr4],      av);
            f4a(*(const float4*)&As[kk][tr4 + 64], av + 4);
            f4a(*(const float4*)&Bs[kk][tc4],      bv);
            f4a(*(const float4*)&Bs[kk][tc4 + 64], bv + 4);
#pragma unroll
            for (int i = 0; i < 8; ++i)
#pragma unroll
                for (int j = 0; j < 8; ++j)
                    acc[i][j] = fmaf(av[i], bv[j], acc[i][j]);
        }
    }
}

// ---------------- QKV projection (fp32, 128x128 tiles) ------------------------
__global__ __launch_bounds__(256) void qkv_kernel(const float* __restrict__ x,
                                                  const float* __restrict__ Wq,
                                                  const float* __restrict__ Wk,
                                                  const float* __restrict__ Wv,
                                                  float* __restrict__ q,
                                                  float* __restrict__ k,
                                                  float* __restrict__ v) {
    __shared__ float As[16][128], Bs[16][128];
    const int mt = blockIdx.x, nt = blockIdx.y, wz = blockIdx.z;
    const float* Wm = (wz == 0) ? Wq : ((wz == 1) ? Wk : Wv);
    float* out = (wz == 0) ? q : ((wz == 1) ? k : v);
    const int t = threadIdx.x;
    const int kq = t >> 4, c16 = (t & 15) << 2;
    const float* ap  = x + (size_t)(mt * 128 + (t >> 1)) * CC;
    // columns nt*128 + [0,64) -> head 2nt; + [64,128) -> head 2nt+1
    const float* bp0 = Wm + ((size_t)(2 * nt)     * CC + kq) * HD + c16;
    const float* bp1 = Wm + ((size_t)(2 * nt + 1) * CC + kq) * HD + c16;
    float acc[8][8] = {};
    sgemm128_core(ap, bp0, bp1, HD, CC, acc, As, Bs);
    const int tr4 = (t >> 4) << 2, tc4 = (t & 15) << 2;
#pragma unroll
    for (int i = 0; i < 8; ++i) {
        const int row = mt * 128 + (i >> 2) * 64 + tr4 + (i & 3);
        float4 o0, o1;
        o0.x = acc[i][0]; o0.y = acc[i][1]; o0.z = acc[i][2]; o0.w = acc[i][3];
        o1.x = acc[i][4]; o1.y = acc[i][5]; o1.z = acc[i][6]; o1.w = acc[i][7];
        *(float4*)&out[(size_t)row * CC + nt * 128 + tc4]      = o0;
        *(float4*)&out[(size_t)row * CC + nt * 128 + 64 + tc4] = o1;
    }
}

// ---------------- plain GEMM + bias (fp32 out-projection) ---------------------
__global__ __launch_bounds__(256) void gemm_bias_kernel(const float* __restrict__ A,
                                                        const float* __restrict__ Bm,
                                                        const float* __restrict__ bias,
                                                        float* __restrict__ out,
                                                        int N, int Kd) {
    __shared__ float As[16][128], Bs[16][128];
    const int mt = blockIdx.x, nt = blockIdx.y;
    const int t = threadIdx.x;
    const int kq = t >> 4, c16 = (t & 15) << 2;
    const float* ap  = A + (size_t)(mt * 128 + (t >> 1)) * Kd;
    const float* bp0 = Bm + (size_t)kq * N + nt * 128 + c16;
    const float* bp1 = bp0 + 64;
    float acc[8][8] = {};
    sgemm128_core(ap, bp0, bp1, N, Kd, acc, As, Bs);
    const int tr4 = (t >> 4) << 2, tc4 = (t & 15) << 2;
    const float4 ba = *(const float4*)&bias[nt * 128 + tc4];
    const float4 bb = *(const float4*)&bias[nt * 128 + 64 + tc4];
#pragma unroll
    for (int i = 0; i < 8; ++i) {
        const int row = mt * 128 + (i >> 2) * 64 + tr4 + (i & 3);
        float4 o0, o1;
        o0.x = acc[i][0] + ba.x; o0.y = acc[i][1] + ba.y;
        o0.z = acc[i][2] + ba.z; o0.w = acc[i][3] + ba.w;
        o1.x = acc[i][4] + bb.x; o1.y = acc[i][5] + bb.y;
        o1.z = acc[i][6] + bb.z; o1.w = acc[i][7] + bb.w;
        *(float4*)&out[(size_t)row * N + nt * 128 + tc4]      = o0;
        *(float4*)&out[(size_t)row * N + nt * 128 + 64 + tc4] = o1;
    }
}

// ---------------- flash-style causal attention, persistent job queue ----------
// Per-tile math / FMA order identical to the passing r2 round (bitwise-same
// routing path). Scheduling: 768 blocks (3/CU, LDS-limited) pull 1024 jobs
// from a global atomic counter, ordered heavy-first (qt = 31 - jid/32).
// Dynamic balancing removes r3's dispatch tail; r2's static pairing removed.
constexpr int ATTN_JOBS = (TT / 64) * HH * BB;   // 1024
__global__ __launch_bounds__(256) void attn_kernel(float* __restrict__ q,
                                                   const float* __restrict__ kbuf,
                                                   const float* __restrict__ vbuf,
                                                   int* __restrict__ jctr) {
    __shared__ float Qs[64][64];
    __shared__ float Ks[64][64];
    __shared__ float Vs[64][64];
    __shared__ int jid_s;
    float (*Ps)[64] = Ks;   // P overwrites K after QK^T consumed it
    const int t = threadIdx.x;
    const int tc4 = (t & 15) << 2, tr4 = (t >> 4) << 2;
    for (;;) {
        __syncthreads();               // protect jid_s and LDS reuse
        if (t == 0) jid_s = atomicAdd(jctr, 1);
        __syncthreads();
        const int jid = jid_s;
        if (jid >= ATTN_JOBS) break;   // uniform exit
        const int qt    = (TT / 64 - 1) - (jid >> 5);   // heavy jobs first
        const int plane = jid & 31;
        const int h = plane & 15, b = plane >> 4;
        const size_t base = ((size_t)b * TT) * CC + h * HD;
#pragma unroll
        for (int it = 0; it < 4; ++it) {
            int fi = t + it * 256;
            int r = fi >> 4, c4 = (fi & 15) << 2;
            *(float4*)&Qs[r][SW(r, c4)] =
                *(const float4*)&q[base + (size_t)(qt * 64 + r) * CC + c4];
        }
        // preload K/V tile 0 into registers
        float4 kr[4], vr[4];
#pragma unroll
        for (int it = 0; it < 4; ++it) {
            int fi = t + it * 256;
            int s = fi >> 4, c4 = (fi & 15) << 2;
            kr[it] = *(const float4*)&kbuf[base + (size_t)s * CC + c4];
            vr[it] = *(const float4*)&vbuf[base + (size_t)s * CC + c4];
        }
        float o[4][4] = {};
        float m_r[4], l_r[4];
#pragma unroll
        for (int i = 0; i < 4; ++i) { m_r[i] = -INFINITY; l_r[i] = 0.0f; }

        for (int kt = 0; kt <= qt; ++kt) {
            __syncthreads();
#pragma unroll
            for (int it = 0; it < 4; ++it) {
                int fi = t + it * 256;
                int s = fi >> 4, c4 = (fi & 15) << 2;
                *(float4*)&Ks[s][SW(s, c4)] = kr[it];
                *(float4*)&Vs[s][SW(s, c4)] = vr[it];
            }
            __syncthreads();
            if (kt < qt) {   // prefetch next K/V tile; completes under compute
#pragma unroll
                for (int it = 0; it < 4; ++it) {
                    int fi = t + it * 256;
                    int s = fi >> 4, c4 = (fi & 15) << 2;
                    kr[it] = *(const float4*)&kbuf[base + (size_t)((kt + 1) * 64 + s) * CC + c4];
                    vr[it] = *(const float4*)&vbuf[base + (size_t)((kt + 1) * 64 + s) * CC + c4];
                }
            }
            float s4[4][4] = {};
            for (int d4 = 0; d4 < 64; d4 += 4) {
                float qa[4][4], ka[4][4];
#pragma unroll
                for (int i = 0; i < 4; ++i)
                    f4a(*(const float4*)&Qs[tr4 + i][SW(tr4 + i, d4)], qa[i]);
#pragma unroll
                for (int j = 0; j < 4; ++j)
                    f4a(*(const float4*)&Ks[tc4 + j][SW(tc4 + j, d4)], ka[j]);
#pragma unroll
                for (int i = 0; i < 4; ++i)
#pragma unroll
                    for (int j = 0; j < 4; ++j) {
                        float a = s4[i][j];
                        a = fmaf(qa[i][0], ka[j][0], a);
                        a = fmaf(qa[i][1], ka[j][1], a);
                        a = fmaf(qa[i][2], ka[j][2], a);
                        a = fmaf(qa[i][3], ka[j][3], a);
                        s4[i][j] = a;
                    }
            }
            const float scale = 0.03125f;  // C^-0.5 (faithful: full C)
#pragma unroll
            for (int i = 0; i < 4; ++i)
#pragma unroll
                for (int j = 0; j < 4; ++j) {
                    float sv = s4[i][j] * scale;
                    if (kt == qt && (tc4 + j) > (tr4 + i)) sv = -INFINITY;
                    s4[i][j] = sv;
                }
            float p4[4][4];
#pragma unroll
            for (int i = 0; i < 4; ++i) {
                float mt_i = fmaxf(fmaxf(s4[i][0], s4[i][1]), fmaxf(s4[i][2], s4[i][3]));
#pragma unroll
                for (int msk = 1; msk <= 8; msk <<= 1) mt_i = fmaxf(mt_i, __shfl_xor(mt_i, msk, 64));
                float m_new = fmaxf(m_r[i], mt_i);
                float alpha = expf(m_r[i] - m_new);
                float ls = 0.0f;
#pragma unroll
                for (int j = 0; j < 4; ++j) {
                    float p = expf(s4[i][j] - m_new);
                    p4[i][j] = p;
                    ls += p;
                }
#pragma unroll
                for (int msk = 1; msk <= 8; msk <<= 1) ls += __shfl_xor(ls, msk, 64);
                l_r[i] = l_r[i] * alpha + ls;
                m_r[i] = m_new;
#pragma unroll
                for (int j = 0; j < 4; ++j) o[i][j] *= alpha;
            }
            __syncthreads();
#pragma unroll
            for (int i = 0; i < 4; ++i) {
                float4 pv;
                pv.x = p4[i][0]; pv.y = p4[i][1]; pv.z = p4[i][2]; pv.w = p4[i][3];
                *(float4*)&Ps[tr4 + i][SW(tr4 + i, tc4)] = pv;
            }
            __syncthreads();
            for (int s0 = 0; s0 < 64; s0 += 4) {
                float pa[4][4], va[4][4];
#pragma unroll
                for (int i = 0; i < 4; ++i)
                    f4a(*(const float4*)&Ps[tr4 + i][SW(tr4 + i, s0)], pa[i]);
#pragma unroll
                for (int qq = 0; qq < 4; ++qq)
                    f4a(*(const float4*)&Vs[s0 + qq][SW(s0 + qq, tc4)], va[qq]);
#pragma unroll
                for (int i = 0; i < 4; ++i)
#pragma unroll
                    for (int j = 0; j < 4; ++j) {
                        float a = o[i][j];
                        a = fmaf(pa[i][0], va[0][j], a);
                        a = fmaf(pa[i][1], va[1][j], a);
                        a = fmaf(pa[i][2], va[2][j], a);
                        a = fmaf(pa[i][3], va[3][j], a);
                        o[i][j] = a;
                    }
            }
        }
#pragma unroll
        for (int i = 0; i < 4; ++i) {
            const float inv = 1.0f / l_r[i];
            float4 o4;
            o4.x = o[i][0] * inv; o4.y = o[i][1] * inv; o4.z = o[i][2] * inv; o4.w = o[i][3] * inv;
            *(float4*)&q[base + (size_t)(qt * 64 + tr4 + i) * CC + tc4] = o4;
        }
    }
}

// ======================= bf16 MFMA blocks (FFN only) ==========================
// Tile 128x128, BK=32, 256 threads = 4 waves 2x2, wave does 4x4 of 16x16x32.
// Register-prefetched staging: raw fp32 for step k0+32 loaded during compute of
// k0; f2bf conversion happens at the LDS-write phase (same values as before).
__device__ __forceinline__ void compute_step(short (*As)[40], short (*Bs)[40],
                                             f32x4 acc[4][4], int wm, int wn,
                                             int l15, int q8) {
    bf16x8 a[4], b[4];
#pragma unroll
    for (int i = 0; i < 4; ++i) a[i] = *(bf16x8*)&As[wm + i * 16 + l15][q8];
#pragma unroll
    for (int j = 0; j < 4; ++j) b[j] = *(bf16x8*)&Bs[wn + j * 16 + l15][q8];
#pragma unroll
    for (int i = 0; i < 4; ++i)
#pragma unroll
        for (int j = 0; j < 4; ++j)
            acc[i][j] = __builtin_amdgcn_mfma_f32_16x16x32_bf16(a[i], b[j], acc[i][j], 0, 0, 0);
}

#define MM_PROLOG                                                    \
    const int t = threadIdx.x, lane = t & 63, wid = t >> 6;          \
    const int wm = (wid >> 1) * 64, wn = (wid & 1) * 64;             \
    const int l15 = lane & 15, q8 = (lane >> 4) * 8;                 \
    const int arow = t >> 1, akh = (t & 1) * 16;                     \
    const int bn = t & 127, bkh = (t >> 7) * 16;

// ---------------- MoE FFN layer 1: gathered rows, +b1, exact GELU -> bf16 hbuf
__global__ __launch_bounds__(256) void mm_ffn1(const float* __restrict__ x1,
                                               const float* __restrict__ W1,
                                               const float* __restrict__ b1,
                                               const int* __restrict__ stok,
                                               const int* __restrict__ offs,
                                               const int* __restrict__ cnt,
                                               short* __restrict__ hbuf, int fbase) {
    __shared__ short As[128][40], Bs[128][40];
    const int e = blockIdx.z, mt = blockIdx.x, nt = blockIdx.y;
    const int ne = cnt[e];
    if (mt * 128 >= ne) return;
    MM_PROLOG
    const int off_e = offs[e];
    int rl = mt * 128 + arow;
    if (rl >= ne) rl = ne - 1;
    const int token = stok[off_e + rl];
    const float* ap = x1 + (size_t)token * CC;
    const float* bp = W1 + (size_t)e * CC * FF + fbase + nt * 128 + bn;
    f32x4 acc[4][4] = {};
    // preload k0 = 0
    float4 apf[4];
    float bpf[16];
#pragma unroll
    for (int qd = 0; qd < 4; ++qd) apf[qd] = *(const float4*)(ap + akh + 4 * qd);
#pragma unroll
    for (int kk = 0; kk < 16; ++kk) bpf[kk] = bp[(size_t)(bkh + kk) * FF];
    for (int k0 = 0; k0 < CC; k0 += 32) {
        __syncthreads();
        *(bf16x8*)&As[arow][akh]     = pack8(apf[0], apf[1]);
        *(bf16x8*)&As[arow][akh + 8] = pack8(apf[2], apf[3]);
        {
            bf16x8 o0, o1;
#pragma unroll
            for (int kk = 0; kk < 8; ++kk) { o0[kk] = f2bf(bpf[kk]); o1[kk] = f2bf(bpf[kk + 8]); }
            *(bf16x8*)&Bs[bn][bkh]     = o0;
            *(bf16x8*)&Bs[bn][bkh + 8] = o1;
        }
        __syncthreads();
        if (k0 + 32 < CC) {
#pragma unroll
            for (int qd = 0; qd < 4; ++qd)
                apf[qd] = *(const float4*)(ap + k0 + 32 + akh + 4 * qd);
#pragma unroll
            for (int kk = 0; kk < 16; ++kk)
                bpf[kk] = bp[(size_t)(k0 + 32 + bkh + kk) * FF];
        }
        compute_step(As, Bs, acc, wm, wn, l15, q8);
    }
    float bj[4];
#pragma unroll
    for (int j = 0; j < 4; ++j)
        bj[j] = b1[(size_t)e * FF + fbase + nt * 128 + wn + j * 16 + l15];
    const int colb = nt * 128 + wn;   // chunk-local column
#pragma unroll
    for (int i = 0; i < 4; ++i) {
#pragma unroll
        for (int r = 0; r < 4; ++r) {
            const int row = mt * 128 + wm + i * 16 + (lane >> 4) * 4 + r;
            if (row < ne) {
                short* orow = hbuf + (size_t)(off_e + row) * FFC + colb;
#pragma unroll
                for (int j = 0; j < 4; ++j)
                    orow[j * 16 + l15] = f2bf(gelu_exact(acc[i][j][r] + bj[j]));
            }
        }
    }
}

// ---------------- MoE FFN layer 2: gate-weighted atomic accumulate -----------
__global__ __launch_bounds__(256) void mm_ffn2(const short* __restrict__ hbuf,
                                               const float* __restrict__ W2,
                                               const float* __restrict__ b2,
                                               const int* __restrict__ stok,
                                               const float* __restrict__ sgate,
                                               const int* __restrict__ offs,
                                               const int* __restrict__ cnt,
                                               float* __restrict__ moe,
                                               int fbase, int first) {
    __shared__ short As[128][40], Bs[128][40];
    const int e = blockIdx.z, mt = blockIdx.x, nt = blockIdx.y;
    const int ne = cnt[e];
    if (mt * 128 >= ne) return;
    MM_PROLOG
    const int off_e = offs[e];
    int rl = mt * 128 + arow;
    if (rl >= ne) rl = ne - 1;
    const short* ap = hbuf + (size_t)(off_e + rl) * FFC;
    const float* bp = W2 + (size_t)e * FF * CC + (size_t)fbase * CC + nt * 128 + bn;
    f32x4 acc[4][4] = {};
    // preload k0 = 0
    bf16x8 a0pf = *(const bf16x8*)(ap + akh);
    bf16x8 a1pf = *(const bf16x8*)(ap + akh + 8);
    float bpf[16];
#pragma unroll
    for (int kk = 0; kk < 16; ++kk) bpf[kk] = bp[(size_t)(bkh + kk) * CC];
    for (int k0 = 0; k0 < FFC; k0 += 32) {
        __syncthreads();
        *(bf16x8*)&As[arow][akh]     = a0pf;
        *(bf16x8*)&As[arow][akh + 8] = a1pf;
        {
            bf16x8 o0, o1;
#pragma unroll
            for (int kk = 0; kk < 8; ++kk) { o0[kk] = f2bf(bpf[kk]); o1[kk] = f2bf(bpf[kk + 8]); }
            *(bf16x8*)&Bs[bn][bkh]     = o0;
            *(bf16x8*)&Bs[bn][bkh + 8] = o1;
        }
        __syncthreads();
        if (k0 + 32 < FFC) {
            a0pf = *(const bf16x8*)(ap + k0 + 32 + akh);
            a1pf = *(const bf16x8*)(ap + k0 + 32 + akh + 8);
#pragma unroll
            for (int kk = 0; kk < 16; ++kk)
                bpf[kk] = bp[(size_t)(k0 + 32 + bkh + kk) * CC];
        }
        compute_step(As, Bs, acc, wm, wn, l15, q8);
    }
    float bj[4];
    int colj[4];
#pragma unroll
    for (int j = 0; j < 4; ++j) {
        colj[j] = nt * 128 + wn + j * 16 + l15;
        bj[j] = first ? b2[(size_t)e * CC + colj[j]] : 0.0f;
    }
#pragma unroll
    for (int i = 0; i < 4; ++i) {
#pragma unroll
        for (int r = 0; r < 4; ++r) {
            const int row = mt * 128 + wm + i * 16 + (lane >> 4) * 4 + r;
            if (row < ne) {
                const int slot = off_e + row;
                const int token = stok[slot];
                const float g = sgate[slot];
                float* dst = moe + (size_t)token * CC;
#pragma unroll
                for (int j = 0; j < 4; ++j)
                    atomicAdd(dst + colj[j], g * (acc[i][j][r] + bj[j]));
            }
        }
    }
}

// ---------------- LayerNorm + residual ----------------------------------------
__device__ __forceinline__ float block_sum(float v, float* red) {
#pragma unroll
    for (int m = 32; m >= 1; m >>= 1) v += __shfl_xor(v, m, 64);
    const int w = threadIdx.x >> 6;
    __syncthreads();
    if ((threadIdx.x & 63) == 0) red[w] = v;
    __syncthreads();
    return red[0] + red[1] + red[2] + red[3];
}

__global__ __launch_bounds__(256) void ln_res_kernel(const float* __restrict__ src,
                                                     const float* __restrict__ res,
                                                     const float* __restrict__ gam,
                                                     const float* __restrict__ bet,
                                                     float* __restrict__ out) {
    __shared__ float red[4];
    const int row = blockIdx.x, t = threadIdx.x;
    const float4 sv = *(const float4*)&src[(size_t)row * CC + t * 4];
    const float total = block_sum(sv.x + sv.y + sv.z + sv.w, red);
    const float mean = total * (1.0f / CC);
    const float d0 = sv.x - mean, d1 = sv.y - mean, d2 = sv.z - mean, d3 = sv.w - mean;
    const float var = block_sum(d0 * d0 + d1 * d1 + d2 * d2 + d3 * d3, red) * (1.0f / CC);
    const float rstd = rsqrtf(var + 1e-5f);
    const float4 rv = *(const float4*)&res[(size_t)row * CC + t * 4];
    const float4 g4 = *(const float4*)&gam[t * 4];
    const float4 b4 = *(const float4*)&bet[t * 4];
    float4 o4;
    o4.x = rv.x + d0 * rstd * g4.x + b4.x;
    o4.y = rv.y + d1 * rstd * g4.y + b4.y;
    o4.z = rv.z + d2 * rstd * g4.z + b4.z;
    o4.w = rv.w + d3 * rstd * g4.w + b4.w;
    *(float4*)&out[(size_t)row * CC + t * 4] = o4;
}

// ---------------- router: noisy top-2 gates + per-expert counts ---------------
__global__ __launch_bounds__(256) void router_kernel(const float* __restrict__ x1,
                                                     const float* __restrict__ Wr,
                                                     const float* __restrict__ br,
                                                     const float* __restrict__ Wn,
                                                     const float* __restrict__ bn,
                                                     const float* __restrict__ noise,
                                                     float* __restrict__ gates,
                                                     int* __restrict__ eids,
                                                     int* __restrict__ counts) {
    __shared__ float xs[CC];
    __shared__ float part[256];
    __shared__ float dots[16];
    const int tk = blockIdx.x, t = threadIdx.x;
    *(float4*)&xs[t * 4] = *(const float4*)&x1[(size_t)tk * CC + t * 4];
    __syncthreads();
    const int o = t & 15, cs = t >> 4;
    float acc = 0.0f;
    if (o < 8) {
        for (int c = cs; c < CC; c += 16) acc += xs[c] * Wr[c * EE + o];
    } else {
        const int e = o - 8;
        for (int c = cs; c < CC; c += 16) acc += xs[c] * Wn[c * EE + e];
    }
    part[t] = acc;
    __syncthreads();
    if (t < 16) {
        float s = 0.0f;
        for (int i = 0; i < 16; ++i) s += part[t + 16 * i];
        dots[t] = s;
    }
    __syncthreads();
    if (t == 0) {
        float noisy[EE];
        for (int e = 0; e < EE; ++e) {
            const float lg = dots[e] + br[e];
            const float nl = dots[8 + e] + bn[e];
            const float sp = fmaxf(nl, 0.0f) + log1pf(expf(-fabsf(nl)));
            noisy[e] = lg + noise[(size_t)tk * EE + e] * sp;
        }
        int e1 = 0; float v1 = noisy[0];
        for (int e = 1; e < EE; ++e) if (noisy[e] > v1) { v1 = noisy[e]; e1 = e; }
        int e2 = -1; float v2 = -INFINITY;
        for (int e = 0; e < EE; ++e) if (e != e1 && noisy[e] > v2) { v2 = noisy[e]; e2 = e; }
        const float ex = expf(v2 - v1);
        const float inv = 1.0f / (1.0f + ex);
        gates[2 * tk] = inv; gates[2 * tk + 1] = ex * inv;
        eids[2 * tk] = e1; eids[2 * tk + 1] = e2;
        atomicAdd(&counts[e1], 1);
        atomicAdd(&counts[e2], 1);
    }
}

__global__ void zero_counts_kernel(int* __restrict__ cnt, int* __restrict__ acnt) {
    if (threadIdx.x < EE) cnt[threadIdx.x] = 0;
    if (threadIdx.x == EE) *acnt = 0;
}

__global__ void offsets_kernel(const int* __restrict__ cnt, int* __restrict__ offs,
                               int* __restrict__ cur) {
    const int t = threadIdx.x;
    if (t == 0) {
        int a = 0;
        for (int e = 0; e < EE; ++e) { offs[e] = a; a += cnt[e]; }
    }
    if (t < EE) cur[t] = 0;
}

__global__ __launch_bounds__(256) void scatter_kernel(const int* __restrict__ eids,
                                                      const float* __restrict__ gates,
                                                      int* __restrict__ cur,
                                                      const int* __restrict__ offs,
                                                      int* __restrict__ slot_token,
                                                      float* __restrict__ slot_gate) {
    const int tk = blockIdx.x * 256 + threadIdx.x;
    if (tk >= BT) return;
#pragma unroll
    for (int ki = 0; ki < 2; ++ki) {
        const int e = eids[2 * tk + ki];
        const int idx = atomicAdd(&cur[e], 1);
        const int slot = offs[e] + idx;
        slot_token[slot] = tk;
        slot_gate[slot] = gates[2 * tk + ki];
    }
}

__global__ __launch_bounds__(256) void zero_kernel(float* __restrict__ p, int n4) {
    const int i = blockIdx.x * 256 + threadIdx.x;
    if (i < n4) ((float4*)p)[i] = make_float4(0.f, 0.f, 0.f, 0.f);
}

// ---------------- launch ------------------------------------------------------
extern "C" void kernel_launch(void* const* d_in, const int* in_sizes, int n_in,
                              void* d_out, int out_size, void* d_ws, size_t ws_size,
                              hipStream_t stream) {
    (void)in_sizes; (void)n_in; (void)out_size; (void)ws_size;
    const float* x    = (const float*)d_in[0];
    const float* Wq   = (const float*)d_in[1];
    const float* Wk   = (const float*)d_in[2];
    const float* Wv   = (const float*)d_in[3];
    const float* Wo   = (const float*)d_in[4];
    const float* bo   = (const float*)d_in[5];
    const float* ln1g = (const float*)d_in[6];
    const float* ln1b = (const float*)d_in[7];
    const float* Wr   = (const float*)d_in[8];
    const float* br   = (const float*)d_in[9];
    const float* Wn   = (const float*)d_in[10];
    const float* bn   = (const float*)d_in[11];
    const float* W1   = (const float*)d_in[12];
    const float* b1   = (const float*)d_in[13];
    const float* W2   = (const float*)d_in[14];
    const float* b2   = (const float*)d_in[15];
    const float* ln2g = (const float*)d_in[16];
    const float* ln2b = (const float*)d_in[17];
    const float* noise= (const float*)d_in[18];
    float* out = (float*)d_out;
    float* ws  = (float*)d_ws;
    int*   iws = (int*)d_ws;

    float* qb    = ws + OFF_Q;     // Q, then attn output (in-place)
    float* kb    = ws + OFF_K;
    float* vb    = ws + OFF_V;
    float* proj  = ws + OFF_V;     // V dead after attention
    float* x1    = out;            // x1 lives in d_out
    short* hbuf  = (short*)(ws + OFF_Q);  // spans Q+K regions: 8192 x 2048 bf16
    float* moe   = ws + OFF_V;     // proj dead after ln1
    float* gates = ws + SM_GATES;
    float* sgate = ws + SM_SGATE;
    int* eids  = iws + SM_EIDS;
    int* stok  = iws + SM_STOK;
    int* cnt   = iws + SM_CNT;
    int* offs  = iws + SM_OFFS;
    int* cur   = iws + SM_CUR;
    int* acnt  = iws + SM_ACNT;

    zero_counts_kernel<<<1, 64, 0, stream>>>(cnt, acnt);
    qkv_kernel<<<dim3(BT / 128, CC / 128, 3), 256, 0, stream>>>(x, Wq, Wk, Wv, qb, kb, vb);
    attn_kernel<<<dim3(768), 256, 0, stream>>>(qb, kb, vb, acnt);
    gemm_bias_kernel<<<dim3(BT / 128, CC / 128), 256, 0, stream>>>(qb, Wo, bo, proj, CC, CC);
    ln_res_kernel<<<BT, 256, 0, stream>>>(proj, x, ln1g, ln1b, x1);
    router_kernel<<<BT, 256, 0, stream>>>(x1, Wr, br, Wn, bn, noise, gates, eids, cnt);
    offsets_kernel<<<1, 64, 0, stream>>>(cnt, offs, cur);
    scatter_kernel<<<BT / 256, 256, 0, stream>>>(eids, gates, cur, offs, stok, sgate);
    zero_kernel<<<(BT * CC / 4 + 255) / 256, 256, 0, stream>>>(moe, BT * CC / 4);
    for (int ccnk = 0; ccnk < FF / FFC; ++ccnk) {
        mm_ffn1<<<dim3(2 * BT / 128, FFC / 128, EE), 256, 0, stream>>>(
            x1, W1, b1, stok, offs, cnt, hbuf, ccnk * FFC);
        mm_ffn2<<<dim3(2 * BT / 128, CC / 128, EE), 256, 0, stream>>>(
            hbuf, W2, b2, stok, sgate, offs, cnt, moe, ccnk * FFC, ccnk == 0 ? 1 : 0);
    }
    ln_res_kernel<<<BT, 256, 0, stream>>>(moe, x1, ln2g, ln2b, out);
}